// Round 2
// 207.505 us; speedup vs baseline: 1.1205x; 1.1205x over previous
//
#include <hip/hip_runtime.h>
#include <stdint.h>

#define B_    16
#define FIN   256
#define FOUT  256
#define FH2   256
#define NMIX  8
#define LAT   512
#define HW    4096
#define MT    64

typedef short bf16x8 __attribute__((ext_vector_type(8)));
typedef float f32x4  __attribute__((ext_vector_type(4)));

// workspace layout (bytes) -- unchanged
#define WS_MIX    0           // [16][8] f32
#define WS_BIAS   1024        // [4][16][256] f32 : in, mid, out, short
#define WS_WIN    131072      // [16][65536] bf16, fragment-packed
#define WS_WMID   2228224     // [16][131072] bf16, fragment-packed (sin/cos interleaved k')
#define WS_WOUT   6422528     // [16][131072] bf16, fragment-packed
#define WS_WSHORT 10616832    // [16][65536] bf16, fragment-packed

__device__ __forceinline__ uint16_t f2bf(float f) {
  uint32_t u = __builtin_bit_cast(uint32_t, f);
  u += 0x7fffu + ((u >> 16) & 1u);
  return (uint16_t)(u >> 16);
}
__device__ __forceinline__ uint32_t pack2(float lo, float hi) {
  return (uint32_t)f2bf(lo) | ((uint32_t)f2bf(hi) << 16);
}

#define MFMA(a, b, c) __builtin_amdgcn_mfma_f32_16x16x32_bf16(a, b, c, 0, 0, 0)

// ---------------- kernel A: mix + biases (one block per sample) ----------------
__global__ void k_mix_bias(const float* __restrict__ lat,
                           const float* __restrict__ w_dyna,
                           const float* __restrict__ b_dyna,
                           const float* __restrict__ b_in_mix,
                           const float* __restrict__ b_mid_mix,
                           const float* __restrict__ b_out_mix,
                           const float* __restrict__ b_short_mix,
                           float* __restrict__ ws_mix,
                           float* __restrict__ ws_bias) {
  __shared__ float smix[NMIX];
  const int t = threadIdx.x;
  const int lane = t & 63, wv = t >> 6;
  const int b = blockIdx.x;
#pragma unroll
  for (int d2 = 0; d2 < 2; d2++) {
    int m = wv * 2 + d2;
    float s = 0.f;
#pragma unroll
    for (int j = 0; j < 8; j++)
      s += lat[b * LAT + j * 64 + lane] * w_dyna[m * LAT + j * 64 + lane];
#pragma unroll
    for (int off = 32; off; off >>= 1) s += __shfl_xor(s, off);
    if (lane == 0) {
      float v = s + b_dyna[m];
      ws_mix[b * NMIX + m] = v;
      smix[m] = v;
    }
  }
  __syncthreads();
  const float* banks[4] = {b_in_mix, b_mid_mix, b_out_mix, b_short_mix};
  for (int pos = t; pos < 1024; pos += 256) {
    int bank = pos >> 8, ch = pos & 255;
    const float* bp = banks[bank];
    float a = 0.f;
#pragma unroll
    for (int m = 0; m < NMIX; m++) a += smix[m] * bp[m * 256 + ch];
    ws_bias[(bank * B_ + b) * 256 + ch] = a;
  }
}

// ---------------- kernel B: mixed per-sample bf16 weights, FRAGMENT-PACKED ----
// (unchanged; k_main consumes the same fragment layout)
__global__ void k_weights(const float* __restrict__ k_in_mix,
                          const float* __restrict__ k_mid_mix,
                          const float* __restrict__ k_out_mix,
                          const float* __restrict__ k_short_mix,
                          const float* __restrict__ ws_mix,
                          uint16_t* __restrict__ w_in,
                          uint16_t* __restrict__ w_mid,
                          uint16_t* __restrict__ w_out,
                          uint16_t* __restrict__ w_short) {
  __shared__ float smix[B_ * NMIX];
  const int t = threadIdx.x;
  if (t < B_ * NMIX) smix[t] = ws_mix[t];
  __syncthreads();
  const int idx = blockIdx.x * 256 + t;  // 0..393215 packed positions
  const float* src;
  uint16_t* dst;
  int sstride, dstride;
  if (idx < 65536) {                      // w_in, KT=8
    int e = idx;
    int j = e & 7, lane = (e >> 3) & 63, ots = (e >> 9) & 3, kt = (e >> 11) & 7, wv = e >> 14;
    int row = wv * 64 + ots * 16 + (lane & 15);
    int k = kt * 32 + (lane >> 4) * 8 + j;
    src = k_in_mix + row * 256 + k; sstride = 65536;
    dst = w_in + e;                 dstride = 65536;
  } else if (idx < 196608) {              // w_mid, KT=16, sin/cos interleave
    int e = idx - 65536;
    int j = e & 7, lane = (e >> 3) & 63, ots = (e >> 9) & 3, kt = (e >> 11) & 15, wv = e >> 15;
    int row = wv * 64 + ots * 16 + (lane & 15);
    int kp = kt * 32 + (lane >> 4) * 8 + j;
    int i = (kp >> 1) + ((kp & 1) << 8);
    src = k_mid_mix + row * 512 + i; sstride = 131072;
    dst = w_mid + e;                 dstride = 131072;
  } else if (idx < 327680) {              // w_out, KT=16, interleave
    int e = idx - 196608;
    int j = e & 7, lane = (e >> 3) & 63, ots = (e >> 9) & 3, kt = (e >> 11) & 15, wv = e >> 15;
    int row = wv * 64 + ots * 16 + (lane & 15);
    int kp = kt * 32 + (lane >> 4) * 8 + j;
    int i = (kp >> 1) + ((kp & 1) << 8);
    src = k_out_mix + row * 512 + i; sstride = 131072;
    dst = w_out + e;                 dstride = 131072;
  } else {                                // w_short, KT=8
    int e = idx - 327680;
    int j = e & 7, lane = (e >> 3) & 63, ots = (e >> 9) & 3, kt = (e >> 11) & 7, wv = e >> 14;
    int row = wv * 64 + ots * 16 + (lane & 15);
    int k = kt * 32 + (lane >> 4) * 8 + j;
    src = k_short_mix + row * 256 + k; sstride = 65536;
    dst = w_short + e;                 dstride = 65536;
  }
  float v[NMIX];
#pragma unroll
  for (int m = 0; m < NMIX; m++) v[m] = src[m * sstride];
  for (int b = 0; b < B_; b++) {
    float a = 0.f;
#pragma unroll
    for (int m = 0; m < NMIX; m++) a += smix[b * NMIX + m] * v[m];
    dst[b * dstride] = f2bf(a);
  }
}

// ---------------- main fused kernel (v2b: MT=64, streamed X, pipelined A-loads,
// conservative __syncthreads everywhere) ----
// Grid: 1024 blocks = 16 samples x 16 position tiles; b = blk & 15.
// LDS 72KB -> 2 blocks/CU (8 waves/CU):
//   Xc: 2 x 4KB double-buffered 32-channel chunks of the X tile (bf16, xor-swizzled)
//   H1: 64KB (64 pos x 512 ch bf16, ctile-xor swizzle); H2 overlays H1.
// short matmul fused into phase A (acc_s lives in registers until the epilogue),
// so X is staged exactly once. Phases B and C are barrier-free 16-step MFMA loops
// with 2-deep register weight prefetch.
__launch_bounds__(256, 2)
__global__ void k_main(const float* __restrict__ x,
                       const float* __restrict__ ws_bias,
                       const uint16_t* __restrict__ w_in,
                       const uint16_t* __restrict__ w_mid,
                       const uint16_t* __restrict__ w_out,
                       const uint16_t* __restrict__ w_short,
                       float* __restrict__ out) {
  __shared__ int4 smem4[73728 / 16];
  char* lds = (char*)smem4;
  char* Xc = lds;            // 2 x 4096 bytes
  char* H1 = lds + 8192;     // 65536 bytes (H2 overlays after barrier)

  const int t = threadIdx.x;
  const int lane = t & 63;
  const int wv = t >> 6;
  const int q = lane >> 4;
  const int n = lane & 15;
  const int b = blockIdx.x & 15;
  const int p0 = (blockIdx.x >> 4) * MT;

  const float* xb = x + (size_t)b * FIN * HW + p0;
  const int xpos = t & 63;   // position this thread stages
  const int xcg = wv;        // 8-channel group this thread stages

  // ---- stage X chunk 0 (channels 0..31) ----
  {
    const float* xs = xb + (size_t)(xcg * 8) * HW + xpos;
    float v[8];
#pragma unroll
    for (int e = 0; e < 8; e++) v[e] = xs[(size_t)e * HW];
    *(int4*)(Xc + xpos * 64 + ((xcg ^ (xpos & 3)) * 16)) =
        make_int4((int)pack2(v[0], v[1]), (int)pack2(v[2], v[3]),
                  (int)pack2(v[4], v[5]), (int)pack2(v[6], v[7]));
  }

  // ---- phase A accumulator init: h = b_in, s = b_short ----
  f32x4 acc_h[4][4], acc_s[4][4];
#pragma unroll
  for (int ots = 0; ots < 4; ots++) {
    const int o = wv * 64 + ots * 16 + q * 4;
    const float4 vi = *(const float4*)&ws_bias[(0 * B_ + b) * 256 + o];
    const float4 vs = *(const float4*)&ws_bias[(3 * B_ + b) * 256 + o];
    f32x4 ah, asv;
    ah[0] = vi.x; ah[1] = vi.y; ah[2] = vi.z; ah[3] = vi.w;
    asv[0] = vs.x; asv[1] = vs.y; asv[2] = vs.z; asv[3] = vs.w;
#pragma unroll
    for (int pt = 0; pt < 4; pt++) { acc_h[ots][pt] = ah; acc_s[ots][pt] = asv; }
  }

  // phase-A weight prefetch (kt=0), issued before the barrier
  const uint16_t* Wi = w_in + (size_t)b * 65536 + wv * 16384 + lane * 8;
  const uint16_t* Ws = w_short + (size_t)b * 65536 + wv * 16384 + lane * 8;
  bf16x8 ai[2][4], asf[2][4];
#pragma unroll
  for (int ots = 0; ots < 4; ots++) {
    ai[0][ots] = *(const bf16x8*)(Wi + ots * 512);
    asf[0][ots] = *(const bf16x8*)(Ws + ots * 512);
  }
  __syncthreads();

  // ---- phase A: h1 = K_in @ X + b_in ; short = K_short @ X + b_short ----
#pragma unroll
  for (int kt = 0; kt < 8; kt++) {
    float xv[8];
    if (kt < 7) {
      // issue next X chunk's global loads early (latency hides under MFMAs)
      const float* xs = xb + (size_t)((kt + 1) * 32 + xcg * 8) * HW + xpos;
#pragma unroll
      for (int e = 0; e < 8; e++) xv[e] = xs[(size_t)e * HW];
      // 1-deep weight prefetch
#pragma unroll
      for (int ots = 0; ots < 4; ots++) {
        ai[(kt + 1) & 1][ots] = *(const bf16x8*)(Wi + (kt + 1) * 2048 + ots * 512);
        asf[(kt + 1) & 1][ots] = *(const bf16x8*)(Ws + (kt + 1) * 2048 + ots * 512);
      }
    }
    const char* Xr = Xc + (kt & 1) * 4096;
    bf16x8 bf[4];
#pragma unroll
    for (int pt = 0; pt < 4; pt++) {
      const int p = pt * 16 + n;
      bf[pt] = *(const bf16x8*)(Xr + p * 64 + ((q ^ (p & 3)) * 16));
    }
#pragma unroll
    for (int ots = 0; ots < 4; ots++) {
#pragma unroll
      for (int pt = 0; pt < 4; pt++) {
        acc_h[ots][pt] = MFMA(ai[kt & 1][ots], bf[pt], acc_h[ots][pt]);
        acc_s[ots][pt] = MFMA(asf[kt & 1][ots], bf[pt], acc_s[ots][pt]);
      }
    }
    if (kt < 7) {
      *(int4*)(Xc + ((kt + 1) & 1) * 4096 + xpos * 64 + ((xcg ^ (xpos & 3)) * 16)) =
          make_int4((int)pack2(xv[0], xv[1]), (int)pack2(xv[2], xv[3]),
                    (int)pack2(xv[4], xv[5]), (int)pack2(xv[6], xv[7]));
      __syncthreads();  // protects X double-buffer
    }
  }

  // ---- complex_wave(h1) -> H1 (k' = 2*o + {0:sin,1:cos}, ctile-xor swizzle) ----
#pragma unroll
  for (int ots = 0; ots < 4; ots++) {
    const int ctile = (wv * 4 + ots) * 4 + q;
#pragma unroll
    for (int pt = 0; pt < 4; pt++) {
      const int p = pt * 16 + n;
      *(int4*)(H1 + p * 1024 + ((ctile ^ (p & 7)) * 16)) = make_int4(
          (int)pack2(__sinf(acc_h[ots][pt][0]), __cosf(acc_h[ots][pt][0])),
          (int)pack2(__sinf(acc_h[ots][pt][1]), __cosf(acc_h[ots][pt][1])),
          (int)pack2(__sinf(acc_h[ots][pt][2]), __cosf(acc_h[ots][pt][2])),
          (int)pack2(__sinf(acc_h[ots][pt][3]), __cosf(acc_h[ots][pt][3])));
    }
  }

  // phase-B prologue: bias init + 2-deep weight prefetch, before the barrier
  const uint16_t* Wm = w_mid + (size_t)b * 131072 + wv * 32768 + lane * 8;
  bf16x8 am[3][4];
#pragma unroll
  for (int ots = 0; ots < 4; ots++) {
    am[0][ots] = *(const bf16x8*)(Wm + ots * 512);
    am[1][ots] = *(const bf16x8*)(Wm + 2048 + ots * 512);
  }
  f32x4 acc2[4][4];
#pragma unroll
  for (int ots = 0; ots < 4; ots++) {
    const int o = wv * 64 + ots * 16 + q * 4;
    const float4 v = *(const float4*)&ws_bias[(1 * B_ + b) * 256 + o];
    f32x4 a2;
    a2[0] = v.x; a2[1] = v.y; a2[2] = v.z; a2[3] = v.w;
#pragma unroll
    for (int pt = 0; pt < 4; pt++) acc2[ots][pt] = a2;
  }
  __syncthreads();  // H1 writes visible to all waves

  // ---- phase B: h2 = K_mid(perm) @ H1c + b_mid (barrier-free) ----
#pragma unroll
  for (int kt = 0; kt < 16; kt++) {
    if (kt < 14) {
#pragma unroll
      for (int ots = 0; ots < 4; ots++)
        am[(kt + 2) % 3][ots] = *(const bf16x8*)(Wm + (kt + 2) * 2048 + ots * 512);
    }
    bf16x8 bf[4];
#pragma unroll
    for (int pt = 0; pt < 4; pt++) {
      const int p = pt * 16 + n;
      bf[pt] = *(const bf16x8*)(H1 + p * 1024 + (((kt * 4 + q) ^ (p & 7)) * 16));
    }
#pragma unroll
    for (int ots = 0; ots < 4; ots++)
#pragma unroll
      for (int pt = 0; pt < 4; pt++)
        acc2[ots][pt] = MFMA(am[kt % 3][ots], bf[pt], acc2[ots][pt]);
  }
  __syncthreads();  // all H1 reads done before overwrite

  // ---- complex_wave(h2) -> H2 (overlays H1 region) ----
#pragma unroll
  for (int ots = 0; ots < 4; ots++) {
    const int ctile = (wv * 4 + ots) * 4 + q;
#pragma unroll
    for (int pt = 0; pt < 4; pt++) {
      const int p = pt * 16 + n;
      *(int4*)(H1 + p * 1024 + ((ctile ^ (p & 7)) * 16)) = make_int4(
          (int)pack2(__sinf(acc2[ots][pt][0]), __cosf(acc2[ots][pt][0])),
          (int)pack2(__sinf(acc2[ots][pt][1]), __cosf(acc2[ots][pt][1])),
          (int)pack2(__sinf(acc2[ots][pt][2]), __cosf(acc2[ots][pt][2])),
          (int)pack2(__sinf(acc2[ots][pt][3]), __cosf(acc2[ots][pt][3])));
    }
  }

  // phase-C prologue: acc3 = short + b_out (in place in acc_s) + 2-deep prefetch
  const uint16_t* Wo = w_out + (size_t)b * 131072 + wv * 32768 + lane * 8;
  bf16x8 ao[3][4];
#pragma unroll
  for (int ots = 0; ots < 4; ots++) {
    ao[0][ots] = *(const bf16x8*)(Wo + ots * 512);
    ao[1][ots] = *(const bf16x8*)(Wo + 2048 + ots * 512);
  }
#pragma unroll
  for (int ots = 0; ots < 4; ots++) {
    const int o = wv * 64 + ots * 16 + q * 4;
    const float4 v = *(const float4*)&ws_bias[(2 * B_ + b) * 256 + o];
#pragma unroll
    for (int pt = 0; pt < 4; pt++) {
      acc_s[ots][pt][0] += v.x; acc_s[ots][pt][1] += v.y;
      acc_s[ots][pt][2] += v.z; acc_s[ots][pt][3] += v.w;
    }
  }
  __syncthreads();  // H2 writes visible

  // ---- phase C: out = K_out(perm) @ H2c + b_out + short (barrier-free) ----
#pragma unroll
  for (int kt = 0; kt < 16; kt++) {
    if (kt < 14) {
#pragma unroll
      for (int ots = 0; ots < 4; ots++)
        ao[(kt + 2) % 3][ots] = *(const bf16x8*)(Wo + (kt + 2) * 2048 + ots * 512);
    }
    bf16x8 bf[4];
#pragma unroll
    for (int pt = 0; pt < 4; pt++) {
      const int p = pt * 16 + n;
      bf[pt] = *(const bf16x8*)(H1 + p * 1024 + (((kt * 4 + q) ^ (p & 7)) * 16));
    }
#pragma unroll
    for (int ots = 0; ots < 4; ots++)
#pragma unroll
      for (int pt = 0; pt < 4; pt++)
        acc_s[ots][pt] = MFMA(ao[kt % 3][ots], bf[pt], acc_s[ots][pt]);
  }

  // ---- store ----
  {
    float* ob = out + (size_t)b * FOUT * HW + p0;
#pragma unroll
    for (int ots = 0; ots < 4; ots++) {
#pragma unroll
      for (int pt = 0; pt < 4; pt++) {
#pragma unroll
        for (int r = 0; r < 4; r++) {
          const int o = wv * 64 + ots * 16 + q * 4 + r;
          ob[(size_t)o * HW + pt * 16 + n] = acc_s[ots][pt][r];
        }
      }
    }
  }
}

extern "C" void kernel_launch(void* const* d_in, const int* in_sizes, int n_in,
                              void* d_out, int out_size, void* d_ws, size_t ws_size,
                              hipStream_t stream) {
  const float* x           = (const float*)d_in[0];
  const float* lat         = (const float*)d_in[1];
  const float* k_in_mix    = (const float*)d_in[2];
  const float* k_mid_mix   = (const float*)d_in[3];
  const float* k_out_mix   = (const float*)d_in[4];
  const float* k_short_mix = (const float*)d_in[5];
  const float* b_in_mix    = (const float*)d_in[6];
  const float* b_mid_mix   = (const float*)d_in[7];
  const float* b_out_mix   = (const float*)d_in[8];
  const float* b_short_mix = (const float*)d_in[9];
  const float* w_dyna      = (const float*)d_in[10];
  const float* b_dyna      = (const float*)d_in[11];

  char* ws = (char*)d_ws;
  float*    ws_mix  = (float*)(ws + WS_MIX);
  float*    ws_bias = (float*)(ws + WS_BIAS);
  uint16_t* w_in    = (uint16_t*)(ws + WS_WIN);
  uint16_t* w_mid   = (uint16_t*)(ws + WS_WMID);
  uint16_t* w_out   = (uint16_t*)(ws + WS_WOUT);
  uint16_t* w_short = (uint16_t*)(ws + WS_WSHORT);
  float* out = (float*)d_out;

  hipLaunchKernelGGL(k_mix_bias, dim3(16), dim3(256), 0, stream,
                     lat, w_dyna, b_dyna, b_in_mix, b_mid_mix, b_out_mix,
                     b_short_mix, ws_mix, ws_bias);
  hipLaunchKernelGGL(k_weights, dim3(1536), dim3(256), 0, stream,
                     k_in_mix, k_mid_mix, k_out_mix, k_short_mix, ws_mix,
                     w_in, w_mid, w_out, w_short);
  hipLaunchKernelGGL(k_main, dim3(1024), dim3(256), 0, stream,
                     x, ws_bias, w_in, w_mid, w_out, w_short, out);
}

// Round 3
// 201.713 us; speedup vs baseline: 1.1527x; 1.0287x over previous
//
#include <hip/hip_runtime.h>
#include <stdint.h>

#define B_    16
#define FIN   256
#define FOUT  256
#define FH2   256
#define NMIX  8
#define LAT   512
#define HW    4096
#define MT    64

typedef short bf16x8 __attribute__((ext_vector_type(8)));
typedef float f32x4  __attribute__((ext_vector_type(4)));

// workspace layout (bytes) -- unchanged
#define WS_MIX    0           // [16][8] f32
#define WS_BIAS   1024        // [4][16][256] f32 : in, mid, out, short
#define WS_WIN    131072      // [16][65536] bf16, fragment-packed
#define WS_WMID   2228224     // [16][131072] bf16, fragment-packed (sin/cos interleaved k')
#define WS_WOUT   6422528     // [16][131072] bf16, fragment-packed
#define WS_WSHORT 10616832    // [16][65536] bf16, fragment-packed

__device__ __forceinline__ uint16_t f2bf(float f) {
  uint32_t u = __builtin_bit_cast(uint32_t, f);
  u += 0x7fffu + ((u >> 16) & 1u);
  return (uint16_t)(u >> 16);
}
__device__ __forceinline__ uint32_t pack2(float lo, float hi) {
  return (uint32_t)f2bf(lo) | ((uint32_t)f2bf(hi) << 16);
}

#define MFMA(a, b, c) __builtin_amdgcn_mfma_f32_16x16x32_bf16(a, b, c, 0, 0, 0)

// ---------------- kernel A: mix + biases (one block per sample) ----------------
__global__ void k_mix_bias(const float* __restrict__ lat,
                           const float* __restrict__ w_dyna,
                           const float* __restrict__ b_dyna,
                           const float* __restrict__ b_in_mix,
                           const float* __restrict__ b_mid_mix,
                           const float* __restrict__ b_out_mix,
                           const float* __restrict__ b_short_mix,
                           float* __restrict__ ws_mix,
                           float* __restrict__ ws_bias) {
  __shared__ float smix[NMIX];
  const int t = threadIdx.x;
  const int lane = t & 63, wv = t >> 6;
  const int b = blockIdx.x;
#pragma unroll
  for (int d2 = 0; d2 < 2; d2++) {
    int m = wv * 2 + d2;
    float s = 0.f;
#pragma unroll
    for (int j = 0; j < 8; j++)
      s += lat[b * LAT + j * 64 + lane] * w_dyna[m * LAT + j * 64 + lane];
#pragma unroll
    for (int off = 32; off; off >>= 1) s += __shfl_xor(s, off);
    if (lane == 0) {
      float v = s + b_dyna[m];
      ws_mix[b * NMIX + m] = v;
      smix[m] = v;
    }
  }
  __syncthreads();
  const float* banks[4] = {b_in_mix, b_mid_mix, b_out_mix, b_short_mix};
  for (int pos = t; pos < 1024; pos += 256) {
    int bank = pos >> 8, ch = pos & 255;
    const float* bp = banks[bank];
    float a = 0.f;
#pragma unroll
    for (int m = 0; m < NMIX; m++) a += smix[m] * bp[m * 256 + ch];
    ws_bias[(bank * B_ + b) * 256 + ch] = a;
  }
}

// ---------------- kernel B: mixed per-sample bf16 weights, FRAGMENT-PACKED ----
// v3: 8 packed elements per thread (one bf16x8 store per sample), float4 loads.
// Same packed layout and accumulation order as before -> bit-identical output.
// Grid: 192 blocks x 256 threads (each thread owns 8 consecutive packed elems).
__global__ void k_weights(const float* __restrict__ k_in_mix,
                          const float* __restrict__ k_mid_mix,
                          const float* __restrict__ k_out_mix,
                          const float* __restrict__ k_short_mix,
                          const float* __restrict__ ws_mix,
                          uint16_t* __restrict__ w_in,
                          uint16_t* __restrict__ w_mid,
                          uint16_t* __restrict__ w_out,
                          uint16_t* __restrict__ w_short) {
  __shared__ float smix[B_ * NMIX];
  const int t = threadIdx.x;
  if (t < B_ * NMIX) smix[t] = ws_mix[t];
  __syncthreads();
  const int e8 = (blockIdx.x * 256 + t) * 8;  // 8-aligned packed position
  const float* srcA;
  uint16_t* dst;
  int sstride, dstride;
  bool ileave;  // block-uniform
  if (e8 < 65536) {                       // w_in, KT=8
    int e = e8;
    int lane = (e >> 3) & 63, ots = (e >> 9) & 3, kt = (e >> 11) & 7, wv = e >> 14;
    int row = wv * 64 + ots * 16 + (lane & 15);
    int k0 = kt * 32 + (lane >> 4) * 8;
    srcA = k_in_mix + row * 256 + k0; sstride = 65536; ileave = false;
    dst = w_in + e;                   dstride = 65536;
  } else if (e8 < 196608) {               // w_mid, KT=16, sin/cos interleave
    int e = e8 - 65536;
    int lane = (e >> 3) & 63, ots = (e >> 9) & 3, kt = (e >> 11) & 15, wv = e >> 15;
    int row = wv * 64 + ots * 16 + (lane & 15);
    int kp0 = kt * 32 + (lane >> 4) * 8;       // 8-aligned -> i0 = kp0/2, 4-aligned
    srcA = k_mid_mix + row * 512 + (kp0 >> 1); sstride = 131072; ileave = true;
    dst = w_mid + e;                           dstride = 131072;
  } else if (e8 < 327680) {               // w_out, KT=16, interleave
    int e = e8 - 196608;
    int lane = (e >> 3) & 63, ots = (e >> 9) & 3, kt = (e >> 11) & 15, wv = e >> 15;
    int row = wv * 64 + ots * 16 + (lane & 15);
    int kp0 = kt * 32 + (lane >> 4) * 8;
    srcA = k_out_mix + row * 512 + (kp0 >> 1); sstride = 131072; ileave = true;
    dst = w_out + e;                           dstride = 131072;
  } else {                                // w_short, KT=8
    int e = e8 - 327680;
    int lane = (e >> 3) & 63, ots = (e >> 9) & 3, kt = (e >> 11) & 7, wv = e >> 14;
    int row = wv * 64 + ots * 16 + (lane & 15);
    int k0 = kt * 32 + (lane >> 4) * 8;
    srcA = k_short_mix + row * 256 + k0; sstride = 65536; ileave = false;
    dst = w_short + e;                   dstride = 65536;
  }
  // srcB offset: non-interleaved -> +4 (elements 4..7); interleaved -> +256 (cos half)
  const int boff = ileave ? 256 : 4;
  float4 va[NMIX], vb[NMIX];
#pragma unroll
  for (int m = 0; m < NMIX; m++) {
    va[m] = *(const float4*)(srcA + m * sstride);
    vb[m] = *(const float4*)(srcA + m * sstride + boff);
  }
  for (int b = 0; b < B_; b++) {
    float4 ra = make_float4(0.f, 0.f, 0.f, 0.f), rb = ra;
#pragma unroll
    for (int m = 0; m < NMIX; m++) {
      const float s = smix[b * NMIX + m];
      ra.x += s * va[m].x; ra.y += s * va[m].y; ra.z += s * va[m].z; ra.w += s * va[m].w;
      rb.x += s * vb[m].x; rb.y += s * vb[m].y; rb.z += s * vb[m].z; rb.w += s * vb[m].w;
    }
    int4 pkt;
    if (ileave) {  // out order: a0,b0,a1,b1,a2,b2,a3,b3  (sin/cos interleave)
      pkt = make_int4((int)pack2(ra.x, rb.x), (int)pack2(ra.y, rb.y),
                      (int)pack2(ra.z, rb.z), (int)pack2(ra.w, rb.w));
    } else {       // out order: a0,a1,a2,a3,b0,b1,b2,b3
      pkt = make_int4((int)pack2(ra.x, ra.y), (int)pack2(ra.z, ra.w),
                      (int)pack2(rb.x, rb.y), (int)pack2(rb.z, rb.w));
    }
    *(int4*)(dst + (size_t)b * dstride) = pkt;
  }
}

// ---------------- main fused kernel (v3) ----
// vs v2b: (1) X stream prefetch distance 2 (ping-pong register sets) so each
// chunk has a full kt-step of latency cover before the barrier drain;
// (2) weight prefetch distance 3 in phases B/C; (3) s_setprio(1) around MFMA
// clusters (2 blocks/CU at different phases -> scheduler has roles to arbitrate).
__launch_bounds__(256, 2)
__global__ void k_main(const float* __restrict__ x,
                       const float* __restrict__ ws_bias,
                       const uint16_t* __restrict__ w_in,
                       const uint16_t* __restrict__ w_mid,
                       const uint16_t* __restrict__ w_out,
                       const uint16_t* __restrict__ w_short,
                       float* __restrict__ out) {
  __shared__ int4 smem4[73728 / 16];
  char* lds = (char*)smem4;
  char* Xc = lds;            // 2 x 4096 bytes
  char* H1 = lds + 8192;     // 65536 bytes (H2 overlays after barrier)

  const int t = threadIdx.x;
  const int lane = t & 63;
  const int wv = t >> 6;
  const int q = lane >> 4;
  const int n = lane & 15;
  const int b = blockIdx.x & 15;
  const int p0 = (blockIdx.x >> 4) * MT;

  const float* xb = x + (size_t)b * FIN * HW + p0;
  const int xpos = t & 63;   // position this thread stages
  const int xcg = wv;        // 8-channel group this thread stages

  // ---- X stream: ping-pong register sets, distance 2 ----
  float xv[2][8];
#pragma unroll
  for (int e = 0; e < 8; e++)
    xv[0][e] = xb[(size_t)(0 * 32 + xcg * 8 + e) * HW + xpos];
#pragma unroll
  for (int e = 0; e < 8; e++)
    xv[1][e] = xb[(size_t)(1 * 32 + xcg * 8 + e) * HW + xpos];
  // write chunk 0 (waits only on xv[0] loads)
  *(int4*)(Xc + xpos * 64 + ((xcg ^ (xpos & 3)) * 16)) =
      make_int4((int)pack2(xv[0][0], xv[0][1]), (int)pack2(xv[0][2], xv[0][3]),
                (int)pack2(xv[0][4], xv[0][5]), (int)pack2(xv[0][6], xv[0][7]));

  // ---- phase A accumulator init: h = b_in, s = b_short ----
  f32x4 acc_h[4][4], acc_s[4][4];
#pragma unroll
  for (int ots = 0; ots < 4; ots++) {
    const int o = wv * 64 + ots * 16 + q * 4;
    const float4 vi = *(const float4*)&ws_bias[(0 * B_ + b) * 256 + o];
    const float4 vs = *(const float4*)&ws_bias[(3 * B_ + b) * 256 + o];
    f32x4 ah, asv;
    ah[0] = vi.x; ah[1] = vi.y; ah[2] = vi.z; ah[3] = vi.w;
    asv[0] = vs.x; asv[1] = vs.y; asv[2] = vs.z; asv[3] = vs.w;
#pragma unroll
    for (int pt = 0; pt < 4; pt++) { acc_h[ots][pt] = ah; acc_s[ots][pt] = asv; }
  }

  // phase-A weight prefetch (kt=0), issued before the barrier
  const uint16_t* Wi = w_in + (size_t)b * 65536 + wv * 16384 + lane * 8;
  const uint16_t* Ws = w_short + (size_t)b * 65536 + wv * 16384 + lane * 8;
  bf16x8 ai[2][4], asf[2][4];
#pragma unroll
  for (int ots = 0; ots < 4; ots++) {
    ai[0][ots] = *(const bf16x8*)(Wi + ots * 512);
    asf[0][ots] = *(const bf16x8*)(Ws + ots * 512);
  }
  __syncthreads();

  // ---- phase A: h1 = K_in @ X + b_in ; short = K_short @ X + b_short ----
  // steady state: step kt reads chunk kt, issues loads for chunk kt+2,
  // writes chunk kt+1 (loaded one full step ago) after the MFMAs.
#pragma unroll
  for (int kt = 0; kt < 8; kt++) {
    if (kt < 6) {
      const float* xs = xb + (size_t)((kt + 2) * 32 + xcg * 8) * HW + xpos;
#pragma unroll
      for (int e = 0; e < 8; e++) xv[kt & 1][e] = xs[(size_t)e * HW];
    }
    if (kt < 7) {
#pragma unroll
      for (int ots = 0; ots < 4; ots++) {
        ai[(kt + 1) & 1][ots] = *(const bf16x8*)(Wi + (kt + 1) * 2048 + ots * 512);
        asf[(kt + 1) & 1][ots] = *(const bf16x8*)(Ws + (kt + 1) * 2048 + ots * 512);
      }
    }
    const char* Xr = Xc + (kt & 1) * 4096;
    bf16x8 bf[4];
#pragma unroll
    for (int pt = 0; pt < 4; pt++) {
      const int p = pt * 16 + n;
      bf[pt] = *(const bf16x8*)(Xr + p * 64 + ((q ^ (p & 3)) * 16));
    }
    __builtin_amdgcn_s_setprio(1);
#pragma unroll
    for (int ots = 0; ots < 4; ots++) {
#pragma unroll
      for (int pt = 0; pt < 4; pt++) {
        acc_h[ots][pt] = MFMA(ai[kt & 1][ots], bf[pt], acc_h[ots][pt]);
        acc_s[ots][pt] = MFMA(asf[kt & 1][ots], bf[pt], acc_s[ots][pt]);
      }
    }
    __builtin_amdgcn_s_setprio(0);
    if (kt < 7) {
      const int s = (kt + 1) & 1;
      *(int4*)(Xc + s * 4096 + xpos * 64 + ((xcg ^ (xpos & 3)) * 16)) =
          make_int4((int)pack2(xv[s][0], xv[s][1]), (int)pack2(xv[s][2], xv[s][3]),
                    (int)pack2(xv[s][4], xv[s][5]), (int)pack2(xv[s][6], xv[s][7]));
      __syncthreads();  // protects X double-buffer
    }
  }

  // ---- complex_wave(h1) -> H1 (k' = 2*o + {0:sin,1:cos}, ctile-xor swizzle) ----
#pragma unroll
  for (int ots = 0; ots < 4; ots++) {
    const int ctile = (wv * 4 + ots) * 4 + q;
#pragma unroll
    for (int pt = 0; pt < 4; pt++) {
      const int p = pt * 16 + n;
      *(int4*)(H1 + p * 1024 + ((ctile ^ (p & 7)) * 16)) = make_int4(
          (int)pack2(__sinf(acc_h[ots][pt][0]), __cosf(acc_h[ots][pt][0])),
          (int)pack2(__sinf(acc_h[ots][pt][1]), __cosf(acc_h[ots][pt][1])),
          (int)pack2(__sinf(acc_h[ots][pt][2]), __cosf(acc_h[ots][pt][2])),
          (int)pack2(__sinf(acc_h[ots][pt][3]), __cosf(acc_h[ots][pt][3])));
    }
  }

  // phase-B prologue: bias init + 3-deep weight prefetch, before the barrier
  const uint16_t* Wm = w_mid + (size_t)b * 131072 + wv * 32768 + lane * 8;
  bf16x8 am[4][4];
#pragma unroll
  for (int ots = 0; ots < 4; ots++) {
    am[0][ots] = *(const bf16x8*)(Wm + 0 * 2048 + ots * 512);
    am[1][ots] = *(const bf16x8*)(Wm + 1 * 2048 + ots * 512);
    am[2][ots] = *(const bf16x8*)(Wm + 2 * 2048 + ots * 512);
  }
  f32x4 acc2[4][4];
#pragma unroll
  for (int ots = 0; ots < 4; ots++) {
    const int o = wv * 64 + ots * 16 + q * 4;
    const float4 v = *(const float4*)&ws_bias[(1 * B_ + b) * 256 + o];
    f32x4 a2;
    a2[0] = v.x; a2[1] = v.y; a2[2] = v.z; a2[3] = v.w;
#pragma unroll
    for (int pt = 0; pt < 4; pt++) acc2[ots][pt] = a2;
  }
  __syncthreads();  // H1 writes visible to all waves

  // ---- phase B: h2 = K_mid(perm) @ H1c + b_mid (barrier-free, 3-deep) ----
#pragma unroll
  for (int kt = 0; kt < 16; kt++) {
    if (kt < 13) {
#pragma unroll
      for (int ots = 0; ots < 4; ots++)
        am[(kt + 3) & 3][ots] = *(const bf16x8*)(Wm + (kt + 3) * 2048 + ots * 512);
    }
    bf16x8 bf[4];
#pragma unroll
    for (int pt = 0; pt < 4; pt++) {
      const int p = pt * 16 + n;
      bf[pt] = *(const bf16x8*)(H1 + p * 1024 + (((kt * 4 + q) ^ (p & 7)) * 16));
    }
    __builtin_amdgcn_s_setprio(1);
#pragma unroll
    for (int ots = 0; ots < 4; ots++)
#pragma unroll
      for (int pt = 0; pt < 4; pt++)
        acc2[ots][pt] = MFMA(am[kt & 3][ots], bf[pt], acc2[ots][pt]);
    __builtin_amdgcn_s_setprio(0);
  }
  __syncthreads();  // all H1 reads done before overwrite

  // ---- complex_wave(h2) -> H2 (overlays H1 region) ----
#pragma unroll
  for (int ots = 0; ots < 4; ots++) {
    const int ctile = (wv * 4 + ots) * 4 + q;
#pragma unroll
    for (int pt = 0; pt < 4; pt++) {
      const int p = pt * 16 + n;
      *(int4*)(H1 + p * 1024 + ((ctile ^ (p & 7)) * 16)) = make_int4(
          (int)pack2(__sinf(acc2[ots][pt][0]), __cosf(acc2[ots][pt][0])),
          (int)pack2(__sinf(acc2[ots][pt][1]), __cosf(acc2[ots][pt][1])),
          (int)pack2(__sinf(acc2[ots][pt][2]), __cosf(acc2[ots][pt][2])),
          (int)pack2(__sinf(acc2[ots][pt][3]), __cosf(acc2[ots][pt][3])));
    }
  }

  // phase-C prologue: acc3 = short + b_out (in place in acc_s) + 3-deep prefetch
  const uint16_t* Wo = w_out + (size_t)b * 131072 + wv * 32768 + lane * 8;
  bf16x8 ao[4][4];
#pragma unroll
  for (int ots = 0; ots < 4; ots++) {
    ao[0][ots] = *(const bf16x8*)(Wo + 0 * 2048 + ots * 512);
    ao[1][ots] = *(const bf16x8*)(Wo + 1 * 2048 + ots * 512);
    ao[2][ots] = *(const bf16x8*)(Wo + 2 * 2048 + ots * 512);
  }
#pragma unroll
  for (int ots = 0; ots < 4; ots++) {
    const int o = wv * 64 + ots * 16 + q * 4;
    const float4 v = *(const float4*)&ws_bias[(2 * B_ + b) * 256 + o];
#pragma unroll
    for (int pt = 0; pt < 4; pt++) {
      acc_s[ots][pt][0] += v.x; acc_s[ots][pt][1] += v.y;
      acc_s[ots][pt][2] += v.z; acc_s[ots][pt][3] += v.w;
    }
  }
  __syncthreads();  // H2 writes visible

  // ---- phase C: out = K_out(perm) @ H2c + b_out + short (barrier-free, 3-deep) ----
#pragma unroll
  for (int kt = 0; kt < 16; kt++) {
    if (kt < 13) {
#pragma unroll
      for (int ots = 0; ots < 4; ots++)
        ao[(kt + 3) & 3][ots] = *(const bf16x8*)(Wo + (kt + 3) * 2048 + ots * 512);
    }
    bf16x8 bf[4];
#pragma unroll
    for (int pt = 0; pt < 4; pt++) {
      const int p = pt * 16 + n;
      bf[pt] = *(const bf16x8*)(H1 + p * 1024 + (((kt * 4 + q) ^ (p & 7)) * 16));
    }
    __builtin_amdgcn_s_setprio(1);
#pragma unroll
    for (int ots = 0; ots < 4; ots++)
#pragma unroll
      for (int pt = 0; pt < 4; pt++)
        acc_s[ots][pt] = MFMA(ao[kt & 3][ots], bf[pt], acc_s[ots][pt]);
    __builtin_amdgcn_s_setprio(0);
  }

  // ---- store ----
  {
    float* ob = out + (size_t)b * FOUT * HW + p0;
#pragma unroll
    for (int ots = 0; ots < 4; ots++) {
#pragma unroll
      for (int pt = 0; pt < 4; pt++) {
#pragma unroll
        for (int r = 0; r < 4; r++) {
          const int o = wv * 64 + ots * 16 + q * 4 + r;
          ob[(size_t)o * HW + pt * 16 + n] = acc_s[ots][pt][r];
        }
      }
    }
  }
}

extern "C" void kernel_launch(void* const* d_in, const int* in_sizes, int n_in,
                              void* d_out, int out_size, void* d_ws, size_t ws_size,
                              hipStream_t stream) {
  const float* x           = (const float*)d_in[0];
  const float* lat         = (const float*)d_in[1];
  const float* k_in_mix    = (const float*)d_in[2];
  const float* k_mid_mix   = (const float*)d_in[3];
  const float* k_out_mix   = (const float*)d_in[4];
  const float* k_short_mix = (const float*)d_in[5];
  const float* b_in_mix    = (const float*)d_in[6];
  const float* b_mid_mix   = (const float*)d_in[7];
  const float* b_out_mix   = (const float*)d_in[8];
  const float* b_short_mix = (const float*)d_in[9];
  const float* w_dyna      = (const float*)d_in[10];
  const float* b_dyna      = (const float*)d_in[11];

  char* ws = (char*)d_ws;
  float*    ws_mix  = (float*)(ws + WS_MIX);
  float*    ws_bias = (float*)(ws + WS_BIAS);
  uint16_t* w_in    = (uint16_t*)(ws + WS_WIN);
  uint16_t* w_mid   = (uint16_t*)(ws + WS_WMID);
  uint16_t* w_out   = (uint16_t*)(ws + WS_WOUT);
  uint16_t* w_short = (uint16_t*)(ws + WS_WSHORT);
  float* out = (float*)d_out;

  hipLaunchKernelGGL(k_mix_bias, dim3(16), dim3(256), 0, stream,
                     lat, w_dyna, b_dyna, b_in_mix, b_mid_mix, b_out_mix,
                     b_short_mix, ws_mix, ws_bias);
  hipLaunchKernelGGL(k_weights, dim3(192), dim3(256), 0, stream,
                     k_in_mix, k_mid_mix, k_out_mix, k_short_mix, ws_mix,
                     w_in, w_mid, w_out, w_short);
  hipLaunchKernelGGL(k_main, dim3(1024), dim3(256), 0, stream,
                     x, ws_bias, w_in, w_mid, w_out, w_short, out);
}